// Round 1
// baseline (135.150 us; speedup 1.0000x reference)
//
#include <hip/hip_runtime.h>
#include <cmath>

typedef __attribute__((ext_vector_type(8))) short bf16x8;
typedef __attribute__((ext_vector_type(4))) float f32x4;
typedef unsigned short u16;
typedef unsigned int u32;

#define OUT1OFF 33554432   // 8*128*128*256
#define LDW 264            // padded bf16 row stride (264*2 = 528 B, 16B-aligned, bank-spread)

__device__ __forceinline__ u16 f2bf(float f) {
  union { float f; u32 u; } v; v.f = f;
  u32 r = v.u + 0x7fffu + ((v.u >> 16) & 1u);  // RNE
  return (u16)(r >> 16);
}

__device__ __forceinline__ float gelu_f(float x) {
  return 0.5f * x * (1.0f + erff(x * 0.7071067811865475f));
}

// ---------------- k1: U = x@Wtop, Y = x@Wbot + b ; W1T bf16 transpose ----------------
__global__ __launch_bounds__(256) void k1_prep(
    const float* __restrict__ x, const float* __restrict__ Wn2e,
    const float* __restrict__ bn2e, const float* __restrict__ W1,
    float* __restrict__ Uw, float* __restrict__ Yw, u16* __restrict__ W1T)
{
  __shared__ float xl[4][256];
  const int t = threadIdx.x;
  const int blk = blockIdx.x;      // 0..255, 4 node-rows each
  const int r0 = blk * 4;
  {
    const int rr = t >> 6, c4 = (t & 63) * 4;
    *(float4*)&xl[rr][c4] = *(const float4*)&x[(r0 + rr) * 256 + c4];
  }
  __syncthreads();
  const int c = t;
  float u0=0.f,u1=0.f,u2=0.f,u3=0.f,y0=0.f,y1=0.f,y2=0.f,y3=0.f;
  #pragma unroll 4
  for (int k = 0; k < 256; ++k) {
    const float wt = Wn2e[k * 256 + c];
    const float wb = Wn2e[(k + 256) * 256 + c];
    const float a0 = xl[0][k], a1 = xl[1][k], a2 = xl[2][k], a3 = xl[3][k];
    u0 = fmaf(a0, wt, u0); u1 = fmaf(a1, wt, u1);
    u2 = fmaf(a2, wt, u2); u3 = fmaf(a3, wt, u3);
    y0 = fmaf(a0, wb, y0); y1 = fmaf(a1, wb, y1);
    y2 = fmaf(a2, wb, y2); y3 = fmaf(a3, wb, y3);
  }
  const float bb = bn2e[c];
  Uw[(r0+0)*256+c]=u0; Uw[(r0+1)*256+c]=u1; Uw[(r0+2)*256+c]=u2; Uw[(r0+3)*256+c]=u3;
  Yw[(r0+0)*256+c]=y0+bb; Yw[(r0+1)*256+c]=y1+bb; Yw[(r0+2)*256+c]=y2+bb; Yw[(r0+3)*256+c]=y3+bb;
  // W1T[n][k] = bf16(W1[k][n]); blocks 0..127 each own one n
  if (blk < 128) W1T[blk * 256 + t] = f2bf(W1[t * 128 + blk]);
}

// ---------------- k2: per (b,i): ez tile -> GEMM2 (MFMA) -> GEMM3 -> e2v ----------------
__global__ __launch_bounds__(512) void k2_e2v(
    const float* __restrict__ Uw, const float* __restrict__ Yw,
    const u16* __restrict__ W1T, const float* __restrict__ b1,
    const float* __restrict__ W2, const float* __restrict__ b2p,
    float* __restrict__ out)
{
  __shared__ u16 ezLds[128 * LDW];     // 67.5 KB, bf16 ez[j][k], padded
  __shared__ u16 w1Lds[128 * LDW];     // 67.5 KB, bf16 W1T[n][k], padded
  __shared__ float uRow[256];
  __shared__ float psumBuf[2][128];
  const int t = threadIdx.x;
  const int blk = blockIdx.x;          // b*128 + i
  const int b = blk >> 7;

  if (t < 64) *(float4*)&uRow[t * 4] = *(const float4*)&Uw[blk * 256 + t * 4];
  {
    const int c4 = (t & 63) * 4, rw = t >> 6;
    #pragma unroll
    for (int it = 0; it < 16; ++it) {
      const int n = it * 8 + rw;
      *(uint2*)&w1Lds[n * LDW + c4] = *(const uint2*)&W1T[n * 256 + c4];
    }
  }
  __syncthreads();
  // ez = gelu(U[i] + Y[j]) -> bf16 LDS. One wave per row per iter, coalesced Y reads.
  {
    const int c4 = (t & 63) * 4, rw = t >> 6;
    const float u0 = uRow[c4+0], u1 = uRow[c4+1], u2 = uRow[c4+2], u3 = uRow[c4+3];
    #pragma unroll 2
    for (int it = 0; it < 16; ++it) {
      const int j = it * 8 + rw;
      const float4 yv = *(const float4*)&Yw[(b * 128 + j) * 256 + c4];
      const u16 p0 = f2bf(gelu_f(u0 + yv.x));
      const u16 p1 = f2bf(gelu_f(u1 + yv.y));
      const u16 p2 = f2bf(gelu_f(u2 + yv.z));
      const u16 p3 = f2bf(gelu_f(u3 + yv.w));
      uint2 w;
      w.x = (u32)p0 | ((u32)p1 << 16);
      w.y = (u32)p2 | ((u32)p3 << 16);
      *(uint2*)&ezLds[j * LDW + c4] = w;
    }
  }
  __syncthreads();
  // GEMM2: h = ez @ W1. 8 waves = 4 M-groups x 2 N-halves. 16x16x32 bf16 MFMA.
  const int w = t >> 6, l = t & 63;
  const int l15 = l & 15, lh = l >> 4;
  const int wm = w >> 1, wn = w & 1;
  const int kg = lh * 8;
  f32x4 acc[2][4];
  #pragma unroll
  for (int mt = 0; mt < 2; ++mt)
    #pragma unroll
    for (int nt = 0; nt < 4; ++nt) acc[mt][nt] = (f32x4){0.f,0.f,0.f,0.f};
  #pragma unroll
  for (int ks = 0; ks < 8; ++ks) {
    const int k = ks * 32 + kg;
    bf16x8 a0 = *(const bf16x8*)&ezLds[(wm * 32 + 0  + l15) * LDW + k];
    bf16x8 a1 = *(const bf16x8*)&ezLds[(wm * 32 + 16 + l15) * LDW + k];
    #pragma unroll
    for (int nt = 0; nt < 4; ++nt) {
      const bf16x8 bv = *(const bf16x8*)&w1Lds[(wn * 64 + nt * 16 + l15) * LDW + k];
      acc[0][nt] = __builtin_amdgcn_mfma_f32_16x16x32_bf16(a0, bv, acc[0][nt], 0, 0, 0);
      acc[1][nt] = __builtin_amdgcn_mfma_f32_16x16x32_bf16(a1, bv, acc[1][nt], 0, 0, 0);
    }
  }
  // GEMM3: e2v_pre[j] = sum_n relu(h[j][n] + b1[n]) * W2[n]; partial over this wave's 64 cols.
  float ps[2][4];
  #pragma unroll
  for (int mt = 0; mt < 2; ++mt) { ps[mt][0]=0.f; ps[mt][1]=0.f; ps[mt][2]=0.f; ps[mt][3]=0.f; }
  #pragma unroll
  for (int nt = 0; nt < 4; ++nt) {
    const int col = wn * 64 + nt * 16 + l15;
    const float bv = b1[col], wv = W2[col];
    #pragma unroll
    for (int mt = 0; mt < 2; ++mt) {
      ps[mt][0] += fmaxf(acc[mt][nt][0] + bv, 0.f) * wv;
      ps[mt][1] += fmaxf(acc[mt][nt][1] + bv, 0.f) * wv;
      ps[mt][2] += fmaxf(acc[mt][nt][2] + bv, 0.f) * wv;
      ps[mt][3] += fmaxf(acc[mt][nt][3] + bv, 0.f) * wv;
    }
  }
  #pragma unroll
  for (int m = 1; m < 16; m <<= 1) {
    #pragma unroll
    for (int mt = 0; mt < 2; ++mt) {
      ps[mt][0] += __shfl_xor(ps[mt][0], m, 64);
      ps[mt][1] += __shfl_xor(ps[mt][1], m, 64);
      ps[mt][2] += __shfl_xor(ps[mt][2], m, 64);
      ps[mt][3] += __shfl_xor(ps[mt][3], m, 64);
    }
  }
  if (l15 == 0) {
    #pragma unroll
    for (int mt = 0; mt < 2; ++mt) {
      const int jb = wm * 32 + mt * 16 + lh * 4;
      psumBuf[wn][jb + 0] = ps[mt][0];
      psumBuf[wn][jb + 1] = ps[mt][1];
      psumBuf[wn][jb + 2] = ps[mt][2];
      psumBuf[wn][jb + 3] = ps[mt][3];
    }
  }
  __syncthreads();
  if (t < 128) {
    const float b2 = b2p[0];
    out[OUT1OFF + blk * 128 + t] = fmaxf(psumBuf[0][t] + psumBuf[1][t] + b2, 0.f);
  }
}

// ---------------- k3: streaming epilogue (HBM-bound) ----------------
__global__ __launch_bounds__(256) void k3_epi(
    const float* __restrict__ Uw, const float* __restrict__ Yw,
    const float* __restrict__ E, float* __restrict__ out)
{
  const float* __restrict__ e2vp = out + OUT1OFF;
  const int t = threadIdx.x;
  const int base = blockIdx.x * 4096;
  #pragma unroll 2
  for (int it = 0; it < 16; ++it) {
    const int gid = base + it * 256 + t;      // float4 index, < 2^23
    const int g = gid >> 6;                   // edge index
    const int c0 = (gid & 63) * 4;
    const int ui = g >> 7;                    // b*128 + i
    const int yi = ((g >> 14) << 7) | (g & 127);  // b*128 + j
    const float e2v = e2vp[g];                // wave-uniform
    float kk = 2.f;
    if (e2v >= 0.2f && e2v < 1.0f) kk -= 2.f * sqrtf(e2v * 1e-9f);
    const float4 uv = *(const float4*)&Uw[ui * 256 + c0];
    const float4 yv = *(const float4*)&Yw[yi * 256 + c0];
    const float4 ev = *(const float4*)&E[gid * 4];
    float4 o;
    {
      const float ez = gelu_f(uv.x + yv.x);
      const float sg = 1.f / (1.f + __expf(-ez));
      o.x = ez + 0.5f * (kk - __expf(sg)) * ev.x;
    }
    {
      const float ez = gelu_f(uv.y + yv.y);
      const float sg = 1.f / (1.f + __expf(-ez));
      o.y = ez + 0.5f * (kk - __expf(sg)) * ev.y;
    }
    {
      const float ez = gelu_f(uv.z + yv.z);
      const float sg = 1.f / (1.f + __expf(-ez));
      o.z = ez + 0.5f * (kk - __expf(sg)) * ev.z;
    }
    {
      const float ez = gelu_f(uv.w + yv.w);
      const float sg = 1.f / (1.f + __expf(-ez));
      o.w = ez + 0.5f * (kk - __expf(sg)) * ev.w;
    }
    *(float4*)&out[gid * 4] = o;
  }
}

extern "C" void kernel_launch(void* const* d_in, const int* in_sizes, int n_in,
                              void* d_out, int out_size, void* d_ws, size_t ws_size,
                              hipStream_t stream) {
  const float* x    = (const float*)d_in[0];   // [1024, 256]
  const float* E    = (const float*)d_in[1];   // [131072, 256]
  const float* Wn2e = (const float*)d_in[2];   // [512, 256]
  const float* bn2e = (const float*)d_in[3];   // [256]
  const float* W1   = (const float*)d_in[4];   // [256, 128]
  const float* b1   = (const float*)d_in[5];   // [128]
  const float* W2   = (const float*)d_in[6];   // [128]
  const float* b2   = (const float*)d_in[7];   // [1]
  float* out = (float*)d_out;

  float* Uw = (float*)d_ws;                    // [1024, 256] f32
  float* Yw = Uw + 262144;                     // [1024, 256] f32
  u16*  W1T = (u16*)(Yw + 262144);             // [128, 256] bf16

  hipLaunchKernelGGL(k1_prep, dim3(256), dim3(256), 0, stream,
                     x, Wn2e, bn2e, W1, Uw, Yw, W1T);
  hipLaunchKernelGGL(k2_e2v, dim3(1024), dim3(512), 0, stream,
                     Uw, Yw, W1T, b1, W2, b2, out);
  hipLaunchKernelGGL(k3_epi, dim3(2048), dim3(256), 0, stream,
                     Uw, Yw, E, out);
}

// Round 2
// 105.891 us; speedup vs baseline: 1.2763x; 1.2763x over previous
//
#include <hip/hip_runtime.h>
#include <cmath>

typedef __attribute__((ext_vector_type(8))) short bf16x8;
typedef __attribute__((ext_vector_type(4))) float f32x4;
typedef unsigned short u16;
typedef unsigned int u32;

#define OUT1OFF 33554432   // 8*128*128*256
#define LDW 264            // padded bf16 row stride

__device__ __forceinline__ u16 f2bf(float f) {
  union { float f; u32 u; } v; v.f = f;
  u32 r = v.u + 0x7fffu + ((v.u >> 16) & 1u);  // RNE
  return (u16)(r >> 16);
}

__device__ __forceinline__ float bf2f(u32 bits16) {
  union { u32 u; float f; } v; v.u = bits16 << 16;
  return v.f;
}

// tanh-form gelu: 0.5x(1+tanh(c(x+0.044715x^3))) = x * sigmoid(2c(x+0.044715x^3))
__device__ __forceinline__ float gelu_t(float x) {
  const float x2 = x * x;
  const float z = 1.5957691216057308f * x * fmaf(0.044715f, x2, 1.0f); // 2c(x+0.044715x^3)
  return x / (1.0f + __expf(-z));
}

// ---------------- k1: U = x@Wtop, Y = x@Wbot + b ; W1T bf16 transpose ----------------
__global__ __launch_bounds__(256) void k1_prep(
    const float* __restrict__ x, const float* __restrict__ Wn2e,
    const float* __restrict__ bn2e, const float* __restrict__ W1,
    float* __restrict__ Uw, float* __restrict__ Yw, u16* __restrict__ W1T)
{
  __shared__ float xl[4][256];
  const int t = threadIdx.x;
  const int blk = blockIdx.x;      // 0..255, 4 node-rows each
  const int r0 = blk * 4;
  {
    const int rr = t >> 6, c4 = (t & 63) * 4;
    *(float4*)&xl[rr][c4] = *(const float4*)&x[(r0 + rr) * 256 + c4];
  }
  __syncthreads();
  const int c = t;
  float u0=0.f,u1=0.f,u2=0.f,u3=0.f,y0=0.f,y1=0.f,y2=0.f,y3=0.f;
  #pragma unroll 4
  for (int k = 0; k < 256; ++k) {
    const float wt = Wn2e[k * 256 + c];
    const float wb = Wn2e[(k + 256) * 256 + c];
    const float a0 = xl[0][k], a1 = xl[1][k], a2 = xl[2][k], a3 = xl[3][k];
    u0 = fmaf(a0, wt, u0); u1 = fmaf(a1, wt, u1);
    u2 = fmaf(a2, wt, u2); u3 = fmaf(a3, wt, u3);
    y0 = fmaf(a0, wb, y0); y1 = fmaf(a1, wb, y1);
    y2 = fmaf(a2, wb, y2); y3 = fmaf(a3, wb, y3);
  }
  const float bb = bn2e[c];
  Uw[(r0+0)*256+c]=u0; Uw[(r0+1)*256+c]=u1; Uw[(r0+2)*256+c]=u2; Uw[(r0+3)*256+c]=u3;
  Yw[(r0+0)*256+c]=y0+bb; Yw[(r0+1)*256+c]=y1+bb; Yw[(r0+2)*256+c]=y2+bb; Yw[(r0+3)*256+c]=y3+bb;
  if (blk < 128) W1T[blk * 256 + t] = f2bf(W1[t * 128 + blk]);
}

// ---- k2: fused. per (b,i): ez -> GEMM2 (MFMA) -> GEMM3 -> e2v,k -> out0 epilogue ----
__global__ __launch_bounds__(512) void k2_fused(
    const float* __restrict__ Uw, const float* __restrict__ Yw,
    const u16* __restrict__ W1T, const float* __restrict__ b1,
    const float* __restrict__ W2, const float* __restrict__ b2p,
    const float* __restrict__ E, float* __restrict__ out)
{
  __shared__ u16 ezLds[128 * LDW];     // 67.5 KB, bf16 ez[j][k]
  __shared__ u16 w1Lds[128 * LDW];     // 67.5 KB, bf16 W1T[n][k]
  __shared__ float uRow[256];          // phase A: U row; later reused as k[j]
  __shared__ float psumBuf[2][128];
  const int t = threadIdx.x;
  const int blk = blockIdx.x;          // b*128 + i
  const int b = blk >> 7;

  if (t < 64) *(float4*)&uRow[t * 4] = *(const float4*)&Uw[blk * 256 + t * 4];
  {
    const int c4 = (t & 63) * 4, rw = t >> 6;
    #pragma unroll
    for (int it = 0; it < 16; ++it) {
      const int n = it * 8 + rw;
      *(uint2*)&w1Lds[n * LDW + c4] = *(const uint2*)&W1T[n * 256 + c4];
    }
  }
  __syncthreads();
  // ez = gelu(U[i] + Y[j]) -> bf16 LDS
  {
    const int c4 = (t & 63) * 4, rw = t >> 6;
    const float u0 = uRow[c4+0], u1 = uRow[c4+1], u2 = uRow[c4+2], u3 = uRow[c4+3];
    #pragma unroll 2
    for (int it = 0; it < 16; ++it) {
      const int j = it * 8 + rw;
      const float4 yv = *(const float4*)&Yw[(b * 128 + j) * 256 + c4];
      const u16 p0 = f2bf(gelu_t(u0 + yv.x));
      const u16 p1 = f2bf(gelu_t(u1 + yv.y));
      const u16 p2 = f2bf(gelu_t(u2 + yv.z));
      const u16 p3 = f2bf(gelu_t(u3 + yv.w));
      uint2 w;
      w.x = (u32)p0 | ((u32)p1 << 16);
      w.y = (u32)p2 | ((u32)p3 << 16);
      *(uint2*)&ezLds[j * LDW + c4] = w;
    }
  }
  __syncthreads();
  // GEMM2: h = ez @ W1. 8 waves = 4 M-groups x 2 N-halves. 16x16x32 bf16 MFMA.
  {
    const int w = t >> 6, l = t & 63;
    const int l15 = l & 15, lh = l >> 4;
    const int wm = w >> 1, wn = w & 1;
    const int kg = lh * 8;
    f32x4 acc[2][4];
    #pragma unroll
    for (int mt = 0; mt < 2; ++mt)
      #pragma unroll
      for (int nt = 0; nt < 4; ++nt) acc[mt][nt] = (f32x4){0.f,0.f,0.f,0.f};
    #pragma unroll
    for (int ks = 0; ks < 8; ++ks) {
      const int k = ks * 32 + kg;
      bf16x8 a0 = *(const bf16x8*)&ezLds[(wm * 32 + 0  + l15) * LDW + k];
      bf16x8 a1 = *(const bf16x8*)&ezLds[(wm * 32 + 16 + l15) * LDW + k];
      #pragma unroll
      for (int nt = 0; nt < 4; ++nt) {
        const bf16x8 bv = *(const bf16x8*)&w1Lds[(wn * 64 + nt * 16 + l15) * LDW + k];
        acc[0][nt] = __builtin_amdgcn_mfma_f32_16x16x32_bf16(a0, bv, acc[0][nt], 0, 0, 0);
        acc[1][nt] = __builtin_amdgcn_mfma_f32_16x16x32_bf16(a1, bv, acc[1][nt], 0, 0, 0);
      }
    }
    // GEMM3 partials: e2v_pre[j] = sum_n relu(h[j][n]+b1[n]) * W2[n]
    float ps[2][4];
    #pragma unroll
    for (int mt = 0; mt < 2; ++mt) { ps[mt][0]=0.f; ps[mt][1]=0.f; ps[mt][2]=0.f; ps[mt][3]=0.f; }
    #pragma unroll
    for (int nt = 0; nt < 4; ++nt) {
      const int col = wn * 64 + nt * 16 + l15;
      const float bv = b1[col], wv = W2[col];
      #pragma unroll
      for (int mt = 0; mt < 2; ++mt) {
        ps[mt][0] += fmaxf(acc[mt][nt][0] + bv, 0.f) * wv;
        ps[mt][1] += fmaxf(acc[mt][nt][1] + bv, 0.f) * wv;
        ps[mt][2] += fmaxf(acc[mt][nt][2] + bv, 0.f) * wv;
        ps[mt][3] += fmaxf(acc[mt][nt][3] + bv, 0.f) * wv;
      }
    }
    #pragma unroll
    for (int m = 1; m < 16; m <<= 1) {
      #pragma unroll
      for (int mt = 0; mt < 2; ++mt) {
        ps[mt][0] += __shfl_xor(ps[mt][0], m, 64);
        ps[mt][1] += __shfl_xor(ps[mt][1], m, 64);
        ps[mt][2] += __shfl_xor(ps[mt][2], m, 64);
        ps[mt][3] += __shfl_xor(ps[mt][3], m, 64);
      }
    }
    if (l15 == 0) {
      #pragma unroll
      for (int mt = 0; mt < 2; ++mt) {
        const int jb = wm * 32 + mt * 16 + lh * 4;
        psumBuf[wn][jb + 0] = ps[mt][0];
        psumBuf[wn][jb + 1] = ps[mt][1];
        psumBuf[wn][jb + 2] = ps[mt][2];
        psumBuf[wn][jb + 3] = ps[mt][3];
      }
    }
  }
  __syncthreads();
  // e2v + curvature k per row j (uRow reused as k[j])
  if (t < 128) {
    const float e2v = fmaxf(psumBuf[0][t] + psumBuf[1][t] + b2p[0], 0.f);
    out[OUT1OFF + blk * 128 + t] = e2v;
    float kk = 2.f;
    if (e2v >= 0.2f && e2v < 1.0f) kk -= 2.f * sqrtf(e2v * 1e-9f);
    uRow[t] = kk;
  }
  __syncthreads();
  // epilogue: out0 = ez + 0.5*(k - exp(sigmoid(ez)))*E for this block's 128x256 slice
  {
    const int rw = t >> 6, c4 = (t & 63) * 4;
    const int eBase = blk * 32768;   // blk*128*256 < 2^25, fits int
    #pragma unroll 4
    for (int it = 0; it < 16; ++it) {
      const int j = it * 8 + rw;
      const float kk = uRow[j];
      const uint2 ezp = *(const uint2*)&ezLds[j * LDW + c4];
      const float4 ev = *(const float4*)&E[eBase + j * 256 + c4];
      const float ez0 = bf2f(ezp.x & 0xffffu), ez1 = bf2f(ezp.x >> 16);
      const float ez2 = bf2f(ezp.y & 0xffffu), ez3 = bf2f(ezp.y >> 16);
      float4 o;
      o.x = ez0 + 0.5f * (kk - __expf(1.f / (1.f + __expf(-ez0)))) * ev.x;
      o.y = ez1 + 0.5f * (kk - __expf(1.f / (1.f + __expf(-ez1)))) * ev.y;
      o.z = ez2 + 0.5f * (kk - __expf(1.f / (1.f + __expf(-ez2)))) * ev.z;
      o.w = ez3 + 0.5f * (kk - __expf(1.f / (1.f + __expf(-ez3)))) * ev.w;
      *(float4*)&out[eBase + j * 256 + c4] = o;
    }
  }
}

extern "C" void kernel_launch(void* const* d_in, const int* in_sizes, int n_in,
                              void* d_out, int out_size, void* d_ws, size_t ws_size,
                              hipStream_t stream) {
  const float* x    = (const float*)d_in[0];   // [1024, 256]
  const float* E    = (const float*)d_in[1];   // [131072, 256]
  const float* Wn2e = (const float*)d_in[2];   // [512, 256]
  const float* bn2e = (const float*)d_in[3];   // [256]
  const float* W1   = (const float*)d_in[4];   // [256, 128]
  const float* b1   = (const float*)d_in[5];   // [128]
  const float* W2   = (const float*)d_in[6];   // [128]
  const float* b2   = (const float*)d_in[7];   // [1]
  float* out = (float*)d_out;

  float* Uw = (float*)d_ws;                    // [1024, 256] f32
  float* Yw = Uw + 262144;                     // [1024, 256] f32
  u16*  W1T = (u16*)(Yw + 262144);             // [128, 256] bf16

  hipLaunchKernelGGL(k1_prep, dim3(256), dim3(256), 0, stream,
                     x, Wn2e, bn2e, W1, Uw, Yw, W1T);
  hipLaunchKernelGGL(k2_fused, dim3(1024), dim3(512), 0, stream,
                     Uw, Yw, W1T, b1, W2, b2, E, out);
}